// Round 1
// baseline (374.730 us; speedup 1.0000x reference)
//
#include <hip/hip_runtime.h>
#include <hip/hip_bf16.h>
#include <cstdint>

#define B_  16
#define TP  4096
#define TQ  512
#define D2_ 256

#define TI 64
#define TJ 64
#define NJT (TQ / TJ)   // 8
#define APAD 264        // 256 + 8 (f16 elems)
#define UTPAD 72        // 64 + 8
#define PPAD 72

typedef _Float16 f16x8 __attribute__((ext_vector_type(8)));
typedef _Float16 f16x4 __attribute__((ext_vector_type(4)));
typedef float    f32x4 __attribute__((ext_vector_type(4)));

// ---------------- kernel 1: udot[b,j] = sum_c U[b,j,c]*qm[b,j]*w_u[c] ----------------
__global__ __launch_bounds__(256) void k_udot(const float* __restrict__ U,
                                              const float* __restrict__ w,
                                              const int* __restrict__ mq,
                                              float* __restrict__ udot) {
  int row = blockIdx.x * 4 + (threadIdx.x >> 6);   // b*TQ + j, 8192 rows total
  int lane = threadIdx.x & 63;
  const float* Ur = U + (size_t)row * D2_;
  f32x4 u  = *(const f32x4*)&Ur[lane * 4];
  f32x4 wu = *(const f32x4*)&w[D2_ + lane * 4];
  float p = u.x * wu.x + u.y * wu.y + u.z * wu.z + u.w * wu.w;
#pragma unroll
  for (int o = 32; o; o >>= 1) p += __shfl_down(p, o);
  if (lane == 0) udot[row] = p * (float)mq[row];
}

// ---------------- kernel 2: flash-style S/softmax/PV + G slices 0..2 + Smax ----------------
__global__ __launch_bounds__(256) void k_main(
    const float* __restrict__ H, const float* __restrict__ U,
    const float* __restrict__ w, const int* __restrict__ mp,
    const int* __restrict__ mq, const float* __restrict__ udot,
    float* __restrict__ SmaxOut, float* __restrict__ G) {

  __shared__ _Float16 AB[2][TI][APAD];      // [0]=A tile (Hm*w_hu), [1]=U tile (row-major)
  __shared__ _Float16 Ut[D2_][UTPAD];       // U tile transposed [c][j]
  __shared__ _Float16 P[4][16][PPAD];       // per-wave P tile
  __shared__ float w_h_s[D2_], w_hu_s[D2_];
  __shared__ float hdot_s[TI], udot_s[TJ], qm_s[TJ];

  const int b   = blockIdx.y;
  const int i0  = blockIdx.x * TI;
  const int tid = threadIdx.x;
  const int lane = tid & 63;
  const int wv  = tid >> 6;
  const int l15 = lane & 15;
  const int g   = lane >> 4;

  w_h_s[tid]  = w[tid];
  w_hu_s[tid] = w[2 * D2_ + tid];
  __syncthreads();

  const float* Hb  = H  + ((size_t)b * TP + i0) * D2_;
  const int*   pmb = mp + b * TP + i0;

  // stage A = f16(Hm * w_hu) and hdot = Hm . w_h
#pragma unroll
  for (int it = 0; it < 16; ++it) {
    int idx4 = it * 256 + tid;
    int r = idx4 >> 6;
    int c = (idx4 & 63) * 4;
    f32x4 h = *(const f32x4*)&Hb[r * D2_ + c];
    float pm = (float)pmb[r];
    h.x *= pm; h.y *= pm; h.z *= pm; h.w *= pm;
    f16x4 a;
    a[0] = (_Float16)(h.x * w_hu_s[c]);
    a[1] = (_Float16)(h.y * w_hu_s[c + 1]);
    a[2] = (_Float16)(h.z * w_hu_s[c + 2]);
    a[3] = (_Float16)(h.w * w_hu_s[c + 3]);
    *(f16x4*)&AB[0][r][c] = a;
    float p = h.x * w_h_s[c] + h.y * w_h_s[c + 1] + h.z * w_h_s[c + 2] + h.w * w_h_s[c + 3];
#pragma unroll
    for (int o = 32; o; o >>= 1) p += __shfl_down(p, o);
    if (lane == 0) hdot_s[r] = p;   // one row per wave per iter
  }
  __syncthreads();

  float hd[4];
#pragma unroll
  for (int reg = 0; reg < 4; ++reg) hd[reg] = hdot_s[wv * 16 + g * 4 + reg];

  f32x4 Oacc[16];
#pragma unroll
  for (int n = 0; n < 16; ++n) Oacc[n] = {0.f, 0.f, 0.f, 0.f};
  float m_r[4] = {-1e30f, -1e30f, -1e30f, -1e30f};
  float l_r[4] = {0.f, 0.f, 0.f, 0.f};

  for (int jt = 0; jt < NJT; ++jt) {
    const float* Ub  = U  + ((size_t)b * TQ + jt * TJ) * D2_;
    const int*   qmb = mq + b * TQ + jt * TJ;
    // stage U tile (both layouts), f16
#pragma unroll
    for (int it = 0; it < 16; ++it) {
      int idx4 = it * 256 + tid;
      int j = idx4 >> 6;
      int c = (idx4 & 63) * 4;
      f32x4 u = *(const f32x4*)&Ub[j * D2_ + c];
      float qm = (float)qmb[j];
      u.x *= qm; u.y *= qm; u.z *= qm; u.w *= qm;
      f16x4 uv;
      uv[0] = (_Float16)u.x; uv[1] = (_Float16)u.y;
      uv[2] = (_Float16)u.z; uv[3] = (_Float16)u.w;
      *(f16x4*)&AB[1][j][c] = uv;
      Ut[c + 0][j] = uv[0];
      Ut[c + 1][j] = uv[1];
      Ut[c + 2][j] = uv[2];
      Ut[c + 3][j] = uv[3];
    }
    if (tid < TJ) {
      udot_s[tid] = udot[b * TQ + jt * TJ + tid];
      qm_s[tid]   = (float)qmb[tid];
    }
    __syncthreads();

    // S tile: wave's 16 rows x 64 cols
    f32x4 Sacc[4];
#pragma unroll
    for (int t = 0; t < 4; ++t) Sacc[t] = {0.f, 0.f, 0.f, 0.f};
#pragma unroll
    for (int ks = 0; ks < 8; ++ks) {
      f16x8 af = *(const f16x8*)&AB[0][wv * 16 + l15][ks * 32 + g * 8];
#pragma unroll
      for (int t = 0; t < 4; ++t) {
        f16x8 bfr = *(const f16x8*)&AB[1][t * 16 + l15][ks * 32 + g * 8];
        Sacc[t] = __builtin_amdgcn_mfma_f32_16x16x32_f16(af, bfr, Sacc[t], 0, 0, 0);
      }
    }

    // bias + online softmax (C layout: row=g*4+reg, col=t*16+l15)
    float ud[4], qv[4];
#pragma unroll
    for (int t = 0; t < 4; ++t) { ud[t] = udot_s[t * 16 + l15]; qv[t] = qm_s[t * 16 + l15]; }

    float Sv[4][4];
    float tmax[4] = {-1e30f, -1e30f, -1e30f, -1e30f};
#pragma unroll
    for (int t = 0; t < 4; ++t)
#pragma unroll
      for (int reg = 0; reg < 4; ++reg) {
        float v = Sacc[t][reg] + hd[reg] + ud[t];
        Sv[t][reg] = v;
        tmax[reg] = fmaxf(tmax[reg], v);   // raw max (mask NOT applied), matches reference
      }
#pragma unroll
    for (int o = 1; o < 16; o <<= 1)
#pragma unroll
      for (int reg = 0; reg < 4; ++reg)
        tmax[reg] = fmaxf(tmax[reg], __shfl_xor(tmax[reg], o));

    float scale[4], psum[4] = {0.f, 0.f, 0.f, 0.f};
#pragma unroll
    for (int reg = 0; reg < 4; ++reg) {
      float mn = fmaxf(m_r[reg], tmax[reg]);
      scale[reg] = __expf(m_r[reg] - mn);
      m_r[reg] = mn;
      l_r[reg] *= scale[reg];
    }
#pragma unroll
    for (int n = 0; n < 16; ++n)
#pragma unroll
      for (int reg = 0; reg < 4; ++reg)
        Oacc[n][reg] *= scale[reg];

#pragma unroll
    for (int t = 0; t < 4; ++t)
#pragma unroll
      for (int reg = 0; reg < 4; ++reg) {
        float p = qv[t] * __expf(Sv[t][reg] - m_r[reg]);
        psum[reg] += p;
        P[wv][g * 4 + reg][t * 16 + l15] = (_Float16)p;
      }
#pragma unroll
    for (int o = 1; o < 16; o <<= 1)
#pragma unroll
      for (int reg = 0; reg < 4; ++reg)
        psum[reg] += __shfl_xor(psum[reg], o);
#pragma unroll
    for (int reg = 0; reg < 4; ++reg) l_r[reg] += psum[reg];

    // P writes are same-wave consumed: drain LDS queue before reads
    asm volatile("s_waitcnt lgkmcnt(0)" ::: "memory");

    // PV: Oacc += P(16x64) @ Utile(64x256)
#pragma unroll
    for (int ks = 0; ks < 2; ++ks) {
      f16x8 pf = *(const f16x8*)&P[wv][l15][ks * 32 + g * 8];
#pragma unroll
      for (int n = 0; n < 16; ++n) {
        f16x8 uf = *(const f16x8*)&Ut[n * 16 + l15][ks * 32 + g * 8];
        Oacc[n] = __builtin_amdgcn_mfma_f32_16x16x32_f16(pf, uf, Oacc[n], 0, 0, 0);
      }
    }
    __syncthreads();   // protect U/Ut/udot_s restaging next iter (and AB reuse below)
  }

  // Smax out (raw row max)
  if (l15 == 0) {
#pragma unroll
    for (int reg = 0; reg < 4; ++reg)
      SmaxOut[b * TP + i0 + wv * 16 + g * 4 + reg] = m_r[reg];
  }

  // normalize and park U_att in LDS (reuse AB region), then coalesced G writes
  float* Uatt = (float*)&AB[0][0][0];   // [TI][260] f32, 66560B <= 67584B
  float inv_l[4];
#pragma unroll
  for (int reg = 0; reg < 4; ++reg) inv_l[reg] = 1.0f / l_r[reg];
#pragma unroll
  for (int n = 0; n < 16; ++n)
#pragma unroll
    for (int reg = 0; reg < 4; ++reg)
      Uatt[(wv * 16 + g * 4 + reg) * 260 + n * 16 + l15] = Oacc[n][reg] * inv_l[reg];
  __syncthreads();

#pragma unroll
  for (int it = 0; it < 16; ++it) {
    int idx4 = it * 256 + tid;
    int r = idx4 >> 6;
    int c = (idx4 & 63) * 4;
    float pm = (float)pmb[r];
    f32x4 h = *(const f32x4*)&Hb[r * D2_ + c];
    h.x *= pm; h.y *= pm; h.z *= pm; h.w *= pm;   // Hm
    f32x4 u;
    u.x = Uatt[r * 260 + c];     u.y = Uatt[r * 260 + c + 1];
    u.z = Uatt[r * 260 + c + 2]; u.w = Uatt[r * 260 + c + 3];
    size_t ro = ((size_t)b * TP + i0 + r) * (4 * D2_);
    *(f32x4*)&G[ro + c] = h;                                        // slice 0: Hm
    f32x4 up; up.x = u.x * pm; up.y = u.y * pm; up.z = u.z * pm; up.w = u.w * pm;
    *(f32x4*)&G[ro + D2_ + c] = up;                                 // slice 1: U_att*pm
    f32x4 hu; hu.x = h.x * u.x; hu.y = h.y * u.y; hu.z = h.z * u.z; hu.w = h.w * u.w;
    *(f32x4*)&G[ro + 2 * D2_ + c] = hu;                             // slice 2: Hm*U_att
  }
}

// ---------------- kernel 3a: per-batch max & sum-exp over Smax ----------------
__global__ __launch_bounds__(256) void k_smax_reduce(const float* __restrict__ Smax,
    const int* __restrict__ mp, float* __restrict__ Mb, float* __restrict__ Lb) {
  int b = blockIdx.x;
  int tid = threadIdx.x;
  const float* S = Smax + b * TP;
  const int* pm = mp + b * TP;
  __shared__ float redm[4], reds[4];
  float mx = -1e30f;
  for (int i = tid; i < TP; i += 256) mx = fmaxf(mx, S[i]);
#pragma unroll
  for (int o = 32; o; o >>= 1) mx = fmaxf(mx, __shfl_down(mx, o));
  if ((tid & 63) == 0) redm[tid >> 6] = mx;
  __syncthreads();
  mx = fmaxf(fmaxf(redm[0], redm[1]), fmaxf(redm[2], redm[3]));
  float s = 0.f;
  for (int i = tid; i < TP; i += 256) s += pm[i] ? __expf(S[i] - mx) : 0.f;
#pragma unroll
  for (int o = 32; o; o >>= 1) s += __shfl_down(s, o);
  if ((tid & 63) == 0) reds[tid >> 6] = s;
  __syncthreads();
  if (tid == 0) { Mb[b] = mx; Lb[b] = reds[0] + reds[1] + reds[2] + reds[3]; }
}

// ---------------- kernel 3b: partial h_att per (b, row-chunk) — deterministic ----------------
__global__ __launch_bounds__(256) void k_hatt(const float* __restrict__ H,
    const float* __restrict__ Smax, const int* __restrict__ mp,
    const float* __restrict__ Mb, const float* __restrict__ Lb,
    float* __restrict__ partial) {
  int b = blockIdx.y;
  int chunk = blockIdx.x;          // 32 chunks of 128 rows
  int c = threadIdx.x;             // 256 cols
  float mx = Mb[b];
  float inv = 1.0f / Lb[b];
  float acc = 0.f;
  int i0 = chunk * 128;
  for (int ii = 0; ii < 128; ++ii) {
    int i = i0 + ii;
    float sm = Smax[b * TP + i];
    float wgt = mp[b * TP + i] ? __expf(sm - mx) * inv : 0.f;
    acc += wgt * H[((size_t)b * TP + i) * D2_ + c];
  }
  partial[((size_t)b * 32 + chunk) * D2_ + c] = acc;
}

// ---------------- kernel 3c: sum partials -> h_att ----------------
__global__ __launch_bounds__(256) void k_hatt_sum(const float* __restrict__ partial,
                                                  float* __restrict__ hatt) {
  int b = blockIdx.x;
  int c = threadIdx.x;
  float s = 0.f;
#pragma unroll
  for (int k = 0; k < 32; ++k) s += partial[((size_t)b * 32 + k) * D2_ + c];
  hatt[b * D2_ + c] = s;
}

// ---------------- kernel 4: G slice 3 = Hm * h_att ----------------
__global__ __launch_bounds__(256) void k_g3(const float* __restrict__ H,
    const int* __restrict__ mp, const float* __restrict__ hatt,
    float* __restrict__ G) {
  const int total = B_ * TP * (D2_ / 4);
  for (int idx = blockIdx.x * 256 + threadIdx.x; idx < total; idx += gridDim.x * 256) {
    int c4 = idx & 63;
    int i = (idx >> 6) & (TP - 1);
    int b = idx >> 18;
    float pm = (float)mp[b * TP + i];
    f32x4 h = *(const f32x4*)&H[((size_t)b * TP + i) * D2_ + c4 * 4];
    f32x4 ha = *(const f32x4*)&hatt[b * D2_ + c4 * 4];
    f32x4 o;
    o.x = h.x * pm * ha.x; o.y = h.y * pm * ha.y;
    o.z = h.z * pm * ha.z; o.w = h.w * pm * ha.w;
    *(f32x4*)&G[((size_t)b * TP + i) * (4 * D2_) + 3 * D2_ + c4 * 4] = o;
  }
}

extern "C" void kernel_launch(void* const* d_in, const int* in_sizes, int n_in,
                              void* d_out, int out_size, void* d_ws, size_t ws_size,
                              hipStream_t stream) {
  const float* H  = (const float*)d_in[0];
  const float* U  = (const float*)d_in[1];
  const float* w  = (const float*)d_in[2];
  const int*   mp = (const int*)d_in[3];
  const int*   mq = (const int*)d_in[4];
  float* G = (float*)d_out;

  float* ws      = (float*)d_ws;
  float* udot    = ws;                       // 8192
  float* Smax    = udot + B_ * TQ;           // 65536
  float* Mb      = Smax + B_ * TP;           // 16
  float* Lb      = Mb + B_;                  // 16
  float* hatt    = Lb + B_;                  // 4096
  float* partial = hatt + B_ * D2_;          // 131072

  k_udot<<<dim3(B_ * TQ / 4), 256, 0, stream>>>(U, w, mq, udot);
  k_main<<<dim3(TP / TI, B_), 256, 0, stream>>>(H, U, w, mp, mq, udot, Smax, G);
  k_smax_reduce<<<dim3(B_), 256, 0, stream>>>(Smax, mp, Mb, Lb);
  k_hatt<<<dim3(32, B_), 256, 0, stream>>>(H, Smax, mp, Mb, Lb, partial);
  k_hatt_sum<<<dim3(B_), 256, 0, stream>>>(partial, hatt);
  k_g3<<<dim3(2048), 256, 0, stream>>>(H, mp, hatt, G);
}